// Round 12
// baseline (479.912 us; speedup 1.0000x reference)
//
#include <hip/hip_runtime.h>
#include <hip/hip_bf16.h>

// Problem constants (match reference)
#define BG    64
#define NPER  4096
#define NTOT  (BG * NPER)       // 262144
#define CC    128
#define EE    4194304
#define KK    3277              // ceil(0.8 * 4096)
#define BK    (BG * KK)         // 209728
#define NBLK  1024              // edge blocks (4096 edges each)

// OUTPUT MODEL (established R0-R9): d_out = out_size 32-BIT words; validation
// reads the UPPER u16 of each word as bf16. Write bf16_bits(v)<<16 per element.
#define OFF_X     0
#define OFF_EDGE  (BK * CC)                 // 26845184  (u32 elements)
#define OFF_BATCH (OFF_EDGE + 2 * EE)       // 35233792
#define OFF_PERM  (OFF_BATCH + BK)          // 35443520

// Scratch carved from the TAIL of chunk 0 (107,380,736 bytes).
// Consumed by edge kernel, then overwritten by gather (launched after).
#define CH0_BYTES ((size_t)OFF_EDGE * 4)
#define A_OFF_B   (CH0_BYTES - (size_t)NTOT * 4)   // score/node_map (1 MB)
#define BO_OFF_B  (A_OFF_B - 8192)                 // prefix[1025]
#define BC_OFF_B  (A_OFF_B - 16384)                // counts[1024]
#define CTRL_OFF_B (A_OFF_B - 16640)               // ctrl[2]: ticket, flag

typedef unsigned long long u64;

static __device__ __forceinline__ unsigned short bf16_bits(float f) {
    __hip_bfloat16 h = __float2bfloat16(f);
    return *reinterpret_cast<unsigned short*>(&h);
}
static __device__ __forceinline__ unsigned obf(float v) {
    return ((unsigned)bf16_bits(v)) << 16;   // bf16 in upper half, 0 lower
}
static __device__ __forceinline__ unsigned ald(const unsigned* p) {
    return __hip_atomic_load(p, __ATOMIC_ACQUIRE, __HIP_MEMORY_SCOPE_AGENT);
}
static __device__ __forceinline__ void ast(unsigned* p, unsigned v) {
    __hip_atomic_store(p, v, __ATOMIC_RELEASE, __HIP_MEMORY_SCOPE_AGENT);
}

// Kernel 1: score = x @ coef (f32; wave per row; f64 accumulate). Also zeros
// the edge-kernel control words each call (graph replay safety).
__global__ void score_kernel(const float* __restrict__ x,
                             const float* __restrict__ coef,
                             float* __restrict__ arr_f,
                             unsigned* __restrict__ ctrl) {
    if (blockIdx.x == 0 && threadIdx.x < 2) ast(&ctrl[threadIdx.x], 0u);

    int lane = threadIdx.x & 63;
    int waveId = (blockIdx.x * blockDim.x + threadIdx.x) >> 6;
    int nWaves = (gridDim.x * blockDim.x) >> 6;

    float2 c = ((const float2*)coef)[lane];

    for (int row = waveId; row < NTOT; row += nWaves) {
        float2 v = ((const float2*)(x + (size_t)row * CC))[lane];
        double s = (double)v.x * (double)c.x + (double)v.y * (double)c.y;
        #pragma unroll
        for (int off = 32; off > 0; off >>= 1)
            s += __shfl_down(s, off, 64);
        if (lane == 0) arr_f[row] = (float)s;
    }
}

// ---- Hybrid bitonic sort (4096 keys, 512 threads, 8 keys/thread) ----
template<int J, int K>
__device__ __forceinline__ void bitonic_phase(u64 (&r)[8], u64* lds, int t) {
    if constexpr (J >= 512) {
        __syncthreads();
        #pragma unroll
        for (int m = 0; m < 8; ++m) lds[(t << 3) | m] = r[m];
        __syncthreads();
        #pragma unroll
        for (int m = 0; m < 8; ++m) {
            int i = (t << 3) | m;
            u64 p = lds[i ^ J];
            bool up    = (i & K) == 0;
            bool lower = (i & J) == 0;
            bool takeMax = (lower != up);
            u64 a = r[m];
            r[m] = takeMax ? (a > p ? a : p) : (a < p ? a : p);
        }
    } else if constexpr (J >= 8) {
        constexpr int jl = J >> 3;
        #pragma unroll
        for (int m = 0; m < 8; ++m) {
            u64 p = __shfl_xor(r[m], jl, 64);
            int i = (t << 3) | m;
            bool up    = (i & K) == 0;
            bool lower = (i & J) == 0;
            bool takeMax = (lower != up);
            u64 a = r[m];
            r[m] = takeMax ? (a > p ? a : p) : (a < p ? a : p);
        }
    } else {
        #pragma unroll
        for (int m = 0; m < 8; ++m) {
            if ((m & J) == 0) {
                int i = (t << 3) | m;
                bool up = (i & K) == 0;
                u64 a = r[m], c = r[m | J];
                if ((a > c) == up) { r[m] = c; r[m | J] = a; }
            }
        }
    }
    if constexpr (J > 1) bitonic_phase<J / 2, K>(r, lds, t);
}

template<int K>
__device__ __forceinline__ void bitonic_stage(u64 (&r)[8], u64* lds, int t) {
    bitonic_phase<K / 2, K>(r, lds, t);
    if constexpr (K < 4096) bitonic_stage<K * 2>(r, lds, t);
}

// Kernel 2: per-graph top-K (descending score, tie -> lower index).
__global__ __launch_bounds__(512) void topk_kernel(float* __restrict__ arr_f,
                                                   unsigned* __restrict__ st_li,
                                                   unsigned* __restrict__ st_gate) {
    __shared__ u64 lds[NPER];
    int b = blockIdx.x;
    int t = threadIdx.x;
    const float* s = arr_f + (b << 12);
    int* node_map = (int*)arr_f;

    float4 v0 = *(const float4*)(s + (t << 3));
    float4 v1 = *(const float4*)(s + (t << 3) + 4);
    float vv[8] = {v0.x, v0.y, v0.z, v0.w, v1.x, v1.y, v1.z, v1.w};
    u64 r[8];
    #pragma unroll
    for (int m = 0; m < 8; ++m) {
        unsigned u = __float_as_uint(vv[m]);
        u = u ^ ((u >> 31) ? 0xFFFFFFFFu : 0x80000000u);  // order-preserving asc
        u = ~u;                                            // descending
        r[m] = ((u64)u << 32) | (unsigned)((t << 3) | m);
    }

    bitonic_stage<2>(r, lds, t);

    #pragma unroll
    for (int m = 0; m < 8; ++m) {
        int rank = (t << 3) | m;
        int li = (int)(r[m] & 0xFFFFFFFFull);
        int g  = (b << 12) + li;
        if (rank < KK) {
            int j = b * KK + rank;
            node_map[g] = j;
            unsigned tt = ~((unsigned)(r[m] >> 32));       // recover exact f32 score
            unsigned u0 = (tt >> 31) ? (tt ^ 0x80000000u) : ~tt;
            float sc = __uint_as_float(u0);
            float gate = 1.0f / (1.0f + expf(-sc));
            st_li[j]   = (unsigned)li;
            st_gate[j] = __float_as_uint(gate);
        } else {
            node_map[g] = -1;
        }
    }
}

// Kernel 3: FUSED edge count + grid scan + stable compaction, single pass.
// All 1024 blocks are co-resident by construction (launch_bounds(256,4) caps
// VGPR<=128 -> 4 blocks/CU x 256 CU = 1024). Last-arriving block (ticket) scans
// the 1024 published counts; everyone spins on one flag. Result is
// arrival-order independent -> deterministic under graph replay.
__global__ __launch_bounds__(256, 4) void edge_fused_kernel(
        const int* __restrict__ edge,
        const int* __restrict__ node_map,
        unsigned* __restrict__ counts,
        unsigned* __restrict__ prefix,
        unsigned* __restrict__ ctrl,
        unsigned* __restrict__ out32) {
    __shared__ u64 sBal[4][16];
    __shared__ unsigned sScan[256];
    __shared__ unsigned sOffTot[2];
    __shared__ int sTicket;

    int b = blockIdx.x;
    int base = b << 12;
    int tid = threadIdx.x;
    int lane = tid & 63, wid = tid >> 6;
    u64 lmask = (1ull << lane) - 1ull;

    // Phase A: read edges once, keep mapped endpoints in registers
    int m0s[16], m1s[16];
    #pragma unroll
    for (int k = 0; k < 16; ++k) {
        int e = base + (k << 8) + tid;
        int m0 = node_map[edge[e]];
        int m1 = node_map[edge[EE + e]];
        m0s[k] = m0; m1s[k] = m1;
        u64 bal = __ballot((m0 | m1) >= 0);   // both >= 0
        if (lane == 0) sBal[wid][k] = bal;
    }
    __syncthreads();

    // per-k exclusive offsets within block (stable by edge index)
    unsigned kwBase[16];
    unsigned cnt = 0;
    #pragma unroll
    for (int k = 0; k < 16; ++k) {
        unsigned p0 = (unsigned)__popcll(sBal[0][k]);
        unsigned p1 = (unsigned)__popcll(sBal[1][k]);
        unsigned p2 = (unsigned)__popcll(sBal[2][k]);
        unsigned p3 = (unsigned)__popcll(sBal[3][k]);
        unsigned wb = (wid > 0 ? p0 : 0u) + (wid > 1 ? p1 : 0u) + (wid > 2 ? p2 : 0u);
        kwBase[k] = cnt + wb;
        cnt += p0 + p1 + p2 + p3;
    }

    if (tid == 0) {
        ast(&counts[b], cnt);
        sTicket = (int)__hip_atomic_fetch_add(&ctrl[0], 1u, __ATOMIC_ACQ_REL,
                                              __HIP_MEMORY_SCOPE_AGENT);
    }
    __syncthreads();

    if (sTicket == NBLK - 1) {   // last block: scan all counts
        unsigned v0 = ald(&counts[tid * 4 + 0]);
        unsigned v1 = ald(&counts[tid * 4 + 1]);
        unsigned v2 = ald(&counts[tid * 4 + 2]);
        unsigned v3 = ald(&counts[tid * 4 + 3]);
        unsigned s0 = v0, s1 = s0 + v1, s2 = s1 + v2, s3 = s2 + v3;
        sScan[tid] = s3;
        __syncthreads();
        #pragma unroll
        for (int off = 1; off < 256; off <<= 1) {
            unsigned add = (tid >= off) ? sScan[tid - off] : 0u;
            __syncthreads();
            sScan[tid] += add;
            __syncthreads();
        }
        unsigned before = tid ? sScan[tid - 1] : 0u;
        ast(&prefix[tid * 4 + 0], before);
        ast(&prefix[tid * 4 + 1], before + s0);
        ast(&prefix[tid * 4 + 2], before + s1);
        ast(&prefix[tid * 4 + 3], before + s2);
        if (tid == 255) ast(&prefix[NBLK], before + s3);
        __syncthreads();
        if (tid == 0) ast(&ctrl[1], 1u);
    }

    if (tid == 0) {
        while (ald(&ctrl[1]) == 0u) { __builtin_amdgcn_s_sleep(8); }
        sOffTot[0] = ald(&prefix[b]);
        sOffTot[1] = ald(&prefix[NBLK]);
    }
    __syncthreads();
    unsigned blockOff = sOffTot[0];
    unsigned nvalid   = sOffTot[1];

    // Phase B: write (valid -> front stable, invalid -> tail as -1)
    unsigned* oe = out32 + OFF_EDGE;
    unsigned NEG1 = obf(-1.0f);
    #pragma unroll
    for (int k = 0; k < 16; ++k) {
        int m0 = m0s[k], m1 = m1s[k];
        bool valid = (m0 | m1) >= 0;
        unsigned validPre = kwBase[k] + (unsigned)__popcll(sBal[wid][k] & lmask);
        unsigned localIdx = (unsigned)((k << 8) + tid);
        unsigned pos;
        unsigned fr, fc;
        if (valid) {
            pos = blockOff + validPre;
            fr = obf((float)m0);
            fc = obf((float)m1);
        } else {
            pos = nvalid + ((unsigned)base - blockOff) + localIdx - validPre;
            fr = NEG1;
            fc = NEG1;
        }
        oe[pos]      = fr;
        oe[EE + pos] = fc;
    }
}

// Kernel 4: gather + finalize. x_pooled = bf16(x[perm]*gate); cg==0 lane also
// rewrites batch/perm in place AFTER its group's reads of those words
// (same-wave program order -> race-free).
__global__ void gather_kernel(const float* __restrict__ x,
                              const unsigned* __restrict__ st_li,
                              const unsigned* __restrict__ st_gate,
                              unsigned* __restrict__ out32) {
    int tid = blockIdx.x * blockDim.x + threadIdx.x;
    int rowsPerGrid = (gridDim.x * blockDim.x) >> 5;
    int rid = tid >> 5;
    int cg  = tid & 31;

    for (int row = rid; row < BK; row += rowsPerGrid) {
        int b  = row / KK;
        int li = (int)st_li[row];
        int node = (b << 12) + li;
        float g = __uint_as_float(st_gate[row]);
        float4 v = ((const float4*)(x + (size_t)node * CC))[cg];
        uint4 o;
        o.x = obf(v.x * g);
        o.y = obf(v.y * g);
        o.z = obf(v.z * g);
        o.w = obf(v.w * g);
        ((uint4*)(out32 + OFF_X))[(size_t)row * 32 + cg] = o;
        if (cg == 0) {
            out32[OFF_BATCH + row] = obf((float)b);
            out32[OFF_PERM + row]  = obf((float)node);
        }
    }
}

extern "C" void kernel_launch(void* const* d_in, const int* in_sizes, int n_in,
                              void* d_out, int out_size, void* d_ws, size_t ws_size,
                              hipStream_t stream) {
    // Resolve inputs by element count (all distinct; proven working R5+).
    const float* x    = nullptr;   // 33,554,432 f32
    const float* coef = nullptr;   // 128 f32
    const int*   edge = nullptr;   // 8,388,608 int32
    for (int i = 0; i < n_in; ++i) {
        switch (in_sizes[i]) {
            case NTOT * CC: x    = (const float*)d_in[i]; break;
            case CC:        coef = (const float*)d_in[i]; break;
            case 2 * EE:    edge = (const int*)d_in[i];   break;
            default: break; // batch unused (static layout 64 x 4096)
        }
    }
    if (!x || !coef || !edge) return;

    char* ob = (char*)d_out;
    unsigned* out32 = (unsigned*)d_out;
    float*    A      = (float*)(ob + A_OFF_B);
    unsigned* counts = (unsigned*)(ob + BC_OFF_B);
    unsigned* prefix = (unsigned*)(ob + BO_OFF_B);
    unsigned* ctrl   = (unsigned*)(ob + CTRL_OFF_B);
    unsigned* st_li   = out32 + OFF_BATCH;   // staged li   (raw u32)
    unsigned* st_gate = out32 + OFF_PERM;    // staged gate (f32 bits)

    score_kernel<<<2048, 256, 0, stream>>>(x, coef, A, ctrl);
    topk_kernel<<<BG, 512, 0, stream>>>(A, st_li, st_gate);
    edge_fused_kernel<<<NBLK, 256, 0, stream>>>(edge, (const int*)A, counts,
                                                prefix, ctrl, out32);
    gather_kernel<<<2048, 256, 0, stream>>>(x, st_li, st_gate, out32);
}

// Round 13
// 217.220 us; speedup vs baseline: 2.2093x; 2.2093x over previous
//
#include <hip/hip_runtime.h>
#include <hip/hip_bf16.h>

// Problem constants (match reference)
#define BG    64
#define NPER  4096
#define NTOT  (BG * NPER)       // 262144
#define CC    128
#define EE    4194304
#define KK    3277              // ceil(0.8 * 4096)
#define BK    (BG * KK)         // 209728
#define NBLK  1024              // edge blocks (4096 edges each)

// OUTPUT MODEL (established R0-R9): d_out = out_size 32-BIT words; validation
// reads the UPPER u16 of each word as bf16. Write bf16_bits(v)<<16 per element.
#define OFF_X     0
#define OFF_EDGE  (BK * CC)                 // 26845184  (u32 elements)
#define OFF_BATCH (OFF_EDGE + 2 * EE)       // 35233792
#define OFF_PERM  (OFF_BATCH + BK)          // 35443520

// Scratch carved from the TAIL of chunk 0 (107,380,736 bytes total).
// Consumed by edge kernels, then overwritten by gather (launched after).
#define CH0_BYTES  ((size_t)OFF_EDGE * 4)
#define A_OFF_B    (CH0_BYTES - (size_t)NTOT * 4)       // node_map (1 MB)
#define BO_OFF_B   (A_OFF_B - 8192)                      // prefix[1025]
#define BC_OFF_B   (A_OFF_B - 16384)                     // counts[1024]
#define CTRL_OFF_B (A_OFF_B - 16640)                     // ctrl[2]
#define PAIRS_OFF_B (CTRL_OFF_B - (size_t)NBLK * 4096 * 4) // packed pairs (16.8 MB)

typedef unsigned long long u64;

static __device__ __forceinline__ unsigned short bf16_bits(float f) {
    __hip_bfloat16 h = __float2bfloat16(f);
    return *reinterpret_cast<unsigned short*>(&h);
}
static __device__ __forceinline__ unsigned obf(float v) {
    return ((unsigned)bf16_bits(v)) << 16;   // bf16 in upper half, 0 lower
}
static __device__ __forceinline__ unsigned ald(const unsigned* p) {
    return __hip_atomic_load(p, __ATOMIC_ACQUIRE, __HIP_MEMORY_SCOPE_AGENT);
}
static __device__ __forceinline__ void ast(unsigned* p, unsigned v) {
    __hip_atomic_store(p, v, __ATOMIC_RELEASE, __HIP_MEMORY_SCOPE_AGENT);
}

// Kernel 1: score = x @ coef (f32; 2 rows per wave, float4/lane; f64 accum).
// Also resets the ticket counter each call (graph replay safety).
__global__ void score_kernel(const float* __restrict__ x,
                             const float* __restrict__ coef,
                             float* __restrict__ arr_f,
                             unsigned* __restrict__ ctrl) {
    if (blockIdx.x == 0 && threadIdx.x < 2) ast(&ctrl[threadIdx.x], 0u);

    int lane = threadIdx.x & 63;
    int half = lane >> 5;
    int cg   = lane & 31;
    int waveId = (blockIdx.x * blockDim.x + threadIdx.x) >> 6;
    int nWaves = (gridDim.x * blockDim.x) >> 6;

    float4 c = ((const float4*)coef)[cg];

    for (int pair = waveId; pair < NTOT / 2; pair += nWaves) {
        int row = 2 * pair + half;
        float4 v = ((const float4*)(x + (size_t)row * CC))[cg];
        double s = (double)v.x * c.x + (double)v.y * c.y
                 + (double)v.z * c.z + (double)v.w * c.w;
        #pragma unroll
        for (int off = 16; off > 0; off >>= 1)
            s += __shfl_xor(s, off, 64);     // stays within each 32-lane half
        if (cg == 0) arr_f[row] = (float)s;
    }
}

// ---- Hybrid bitonic sort (4096 keys, 512 threads, 8 keys/thread) ----
template<int J, int K>
__device__ __forceinline__ void bitonic_phase(u64 (&r)[8], u64* lds, int t) {
    if constexpr (J >= 512) {
        __syncthreads();
        #pragma unroll
        for (int m = 0; m < 8; ++m) lds[(t << 3) | m] = r[m];
        __syncthreads();
        #pragma unroll
        for (int m = 0; m < 8; ++m) {
            int i = (t << 3) | m;
            u64 p = lds[i ^ J];
            bool up    = (i & K) == 0;
            bool lower = (i & J) == 0;
            bool takeMax = (lower != up);
            u64 a = r[m];
            r[m] = takeMax ? (a > p ? a : p) : (a < p ? a : p);
        }
    } else if constexpr (J >= 8) {
        constexpr int jl = J >> 3;
        #pragma unroll
        for (int m = 0; m < 8; ++m) {
            u64 p = __shfl_xor(r[m], jl, 64);
            int i = (t << 3) | m;
            bool up    = (i & K) == 0;
            bool lower = (i & J) == 0;
            bool takeMax = (lower != up);
            u64 a = r[m];
            r[m] = takeMax ? (a > p ? a : p) : (a < p ? a : p);
        }
    } else {
        #pragma unroll
        for (int m = 0; m < 8; ++m) {
            if ((m & J) == 0) {
                int i = (t << 3) | m;
                bool up = (i & K) == 0;
                u64 a = r[m], c = r[m | J];
                if ((a > c) == up) { r[m] = c; r[m | J] = a; }
            }
        }
    }
    if constexpr (J > 1) bitonic_phase<J / 2, K>(r, lds, t);
}

template<int K>
__device__ __forceinline__ void bitonic_stage(u64 (&r)[8], u64* lds, int t) {
    bitonic_phase<K / 2, K>(r, lds, t);
    if constexpr (K < 4096) bitonic_stage<K * 2>(r, lds, t);
}

// Kernel 2: per-graph top-K (descending score, tie -> lower index).
__global__ __launch_bounds__(512) void topk_kernel(float* __restrict__ arr_f,
                                                   unsigned* __restrict__ st_li,
                                                   unsigned* __restrict__ st_gate) {
    __shared__ u64 lds[NPER];
    int b = blockIdx.x;
    int t = threadIdx.x;
    const float* s = arr_f + (b << 12);
    int* node_map = (int*)arr_f;

    float4 v0 = *(const float4*)(s + (t << 3));
    float4 v1 = *(const float4*)(s + (t << 3) + 4);
    float vv[8] = {v0.x, v0.y, v0.z, v0.w, v1.x, v1.y, v1.z, v1.w};
    u64 r[8];
    #pragma unroll
    for (int m = 0; m < 8; ++m) {
        unsigned u = __float_as_uint(vv[m]);
        u = u ^ ((u >> 31) ? 0xFFFFFFFFu : 0x80000000u);  // order-preserving asc
        u = ~u;                                            // descending
        r[m] = ((u64)u << 32) | (unsigned)((t << 3) | m);
    }

    bitonic_stage<2>(r, lds, t);

    #pragma unroll
    for (int m = 0; m < 8; ++m) {
        int rank = (t << 3) | m;
        int li = (int)(r[m] & 0xFFFFFFFFull);
        int g  = (b << 12) + li;
        if (rank < KK) {
            int j = b * KK + rank;
            node_map[g] = j;
            unsigned tt = ~((unsigned)(r[m] >> 32));       // recover exact f32 score
            unsigned u0 = (tt >> 31) ? (tt ^ 0x80000000u) : ~tt;
            float sc = __uint_as_float(u0);
            float gate = 1.0f / (1.0f + expf(-sc));
            st_li[j]   = (unsigned)li;
            st_gate[j] = __float_as_uint(gate);
        } else {
            node_map[g] = -1;
        }
    }
}

// Kernel 3: edge pass 1 — single edge read, local stable compaction of packed
// bf16 pairs into scratch, publish count. Last-arriving block (ticket) scans
// all 1024 counts into prefix[]. NOBODY WAITS (R12 lesson: grid-wide spins on
// this chip are a 10x regression; the kernel boundary is the barrier).
__global__ __launch_bounds__(256) void edge_pass1(
        const int* __restrict__ edge,
        const int* __restrict__ node_map,
        unsigned* __restrict__ pairs,
        unsigned* __restrict__ counts,
        unsigned* __restrict__ prefix,
        unsigned* __restrict__ ctrl) {
    __shared__ u64 sBal[4][16];
    __shared__ unsigned sScan[256];
    __shared__ int sTicket;

    int b = blockIdx.x;
    int base = b << 12;
    int tid = threadIdx.x;
    int lane = tid & 63, wid = tid >> 6;
    u64 lmask = (1ull << lane) - 1ull;

    int m0s[16], m1s[16];
    #pragma unroll
    for (int k = 0; k < 16; ++k) {
        int e = base + (k << 8) + tid;
        int m0 = node_map[edge[e]];
        int m1 = node_map[edge[EE + e]];
        m0s[k] = m0; m1s[k] = m1;
        u64 bal = __ballot((m0 | m1) >= 0);
        if (lane == 0) sBal[wid][k] = bal;
    }
    __syncthreads();

    unsigned kwBase[16];
    unsigned cnt = 0;
    #pragma unroll
    for (int k = 0; k < 16; ++k) {
        unsigned p0 = (unsigned)__popcll(sBal[0][k]);
        unsigned p1 = (unsigned)__popcll(sBal[1][k]);
        unsigned p2 = (unsigned)__popcll(sBal[2][k]);
        unsigned p3 = (unsigned)__popcll(sBal[3][k]);
        unsigned wb = (wid > 0 ? p0 : 0u) + (wid > 1 ? p1 : 0u) + (wid > 2 ? p2 : 0u);
        kwBase[k] = cnt + wb;
        cnt += p0 + p1 + p2 + p3;
    }

    // locally-compacted packed pairs (stable by edge index)
    unsigned* pb = pairs + base;
    #pragma unroll
    for (int k = 0; k < 16; ++k) {
        int m0 = m0s[k], m1 = m1s[k];
        if ((m0 | m1) >= 0) {
            unsigned vp = kwBase[k] + (unsigned)__popcll(sBal[wid][k] & lmask);
            pb[vp] = obf((float)m0) | (unsigned)bf16_bits((float)m1);
        }
    }

    if (tid == 0) {
        ast(&counts[b], cnt);
        sTicket = (int)__hip_atomic_fetch_add(&ctrl[0], 1u, __ATOMIC_ACQ_REL,
                                              __HIP_MEMORY_SCOPE_AGENT);
    }
    __syncthreads();

    if (sTicket == NBLK - 1) {     // last block: scan counts -> prefix (no one waits)
        unsigned v0 = ald(&counts[tid * 4 + 0]);
        unsigned v1 = ald(&counts[tid * 4 + 1]);
        unsigned v2 = ald(&counts[tid * 4 + 2]);
        unsigned v3 = ald(&counts[tid * 4 + 3]);
        unsigned s0 = v0, s1 = s0 + v1, s2 = s1 + v2, s3 = s2 + v3;
        sScan[tid] = s3;
        __syncthreads();
        #pragma unroll
        for (int off = 1; off < 256; off <<= 1) {
            unsigned add = (tid >= off) ? sScan[tid - off] : 0u;
            __syncthreads();
            sScan[tid] += add;
            __syncthreads();
        }
        unsigned before = tid ? sScan[tid - 1] : 0u;
        prefix[tid * 4 + 0] = before;
        prefix[tid * 4 + 1] = before + s0;
        prefix[tid * 4 + 2] = before + s1;
        prefix[tid * 4 + 3] = before + s2;
        if (tid == 255) prefix[NBLK] = before + s3;
    }
}

// Kernel 4: edge pass 2 — pure streaming. Front: copy packed pairs to
// [prefix[b], prefix[b]+cnt). Tail: block b's invalid slots form the
// CONTIGUOUS range [nvalid + base - prefix[b], +4096-cnt) -> fill with -1.
__global__ __launch_bounds__(256) void edge_pass2(
        const unsigned* __restrict__ pairs,
        const unsigned* __restrict__ prefix,
        unsigned* __restrict__ out32) {
    int b = blockIdx.x;
    unsigned base = (unsigned)(b << 12);
    unsigned tid = threadIdx.x;
    unsigned blockOff = prefix[b];
    unsigned cnt = prefix[b + 1] - blockOff;
    unsigned nvalid = prefix[NBLK];
    unsigned* oe = out32 + OFF_EDGE;
    const unsigned* pb = pairs + base;

    for (unsigned i = tid; i < cnt; i += 256u) {
        unsigned w = pb[i];
        oe[blockOff + i]      = w & 0xFFFF0000u;
        oe[EE + blockOff + i] = w << 16;
    }
    unsigned tailBase = nvalid + base - blockOff;
    unsigned tcnt = 4096u - cnt;
    unsigned NEG1 = obf(-1.0f);
    for (unsigned i = tid; i < tcnt; i += 256u) {
        oe[tailBase + i]      = NEG1;
        oe[EE + tailBase + i] = NEG1;
    }
}

// Kernel 5: gather + finalize. x_pooled = bf16(x[perm]*gate); cg==0 lane also
// rewrites batch/perm in place AFTER its group's reads (same-wave program
// order -> race-free).
__global__ void gather_kernel(const float* __restrict__ x,
                              const unsigned* __restrict__ st_li,
                              const unsigned* __restrict__ st_gate,
                              unsigned* __restrict__ out32) {
    int tid = blockIdx.x * blockDim.x + threadIdx.x;
    int rowsPerGrid = (gridDim.x * blockDim.x) >> 5;
    int rid = tid >> 5;
    int cg  = tid & 31;

    for (int row = rid; row < BK; row += rowsPerGrid) {
        int b  = row / KK;
        int li = (int)st_li[row];
        int node = (b << 12) + li;
        float g = __uint_as_float(st_gate[row]);
        float4 v = ((const float4*)(x + (size_t)node * CC))[cg];
        uint4 o;
        o.x = obf(v.x * g);
        o.y = obf(v.y * g);
        o.z = obf(v.z * g);
        o.w = obf(v.w * g);
        ((uint4*)(out32 + OFF_X))[(size_t)row * 32 + cg] = o;
        if (cg == 0) {
            out32[OFF_BATCH + row] = obf((float)b);
            out32[OFF_PERM + row]  = obf((float)node);
        }
    }
}

extern "C" void kernel_launch(void* const* d_in, const int* in_sizes, int n_in,
                              void* d_out, int out_size, void* d_ws, size_t ws_size,
                              hipStream_t stream) {
    // Resolve inputs by element count (all distinct; proven working R5+).
    const float* x    = nullptr;   // 33,554,432 f32
    const float* coef = nullptr;   // 128 f32
    const int*   edge = nullptr;   // 8,388,608 int32
    for (int i = 0; i < n_in; ++i) {
        switch (in_sizes[i]) {
            case NTOT * CC: x    = (const float*)d_in[i]; break;
            case CC:        coef = (const float*)d_in[i]; break;
            case 2 * EE:    edge = (const int*)d_in[i];   break;
            default: break; // batch unused (static layout 64 x 4096)
        }
    }
    if (!x || !coef || !edge) return;

    char* ob = (char*)d_out;
    unsigned* out32 = (unsigned*)d_out;
    float*    A      = (float*)(ob + A_OFF_B);
    unsigned* counts = (unsigned*)(ob + BC_OFF_B);
    unsigned* prefix = (unsigned*)(ob + BO_OFF_B);
    unsigned* ctrl   = (unsigned*)(ob + CTRL_OFF_B);
    unsigned* pairs  = (unsigned*)(ob + PAIRS_OFF_B);
    unsigned* st_li   = out32 + OFF_BATCH;   // staged li   (raw u32)
    unsigned* st_gate = out32 + OFF_PERM;    // staged gate (f32 bits)

    score_kernel<<<2048, 256, 0, stream>>>(x, coef, A, ctrl);
    topk_kernel<<<BG, 512, 0, stream>>>(A, st_li, st_gate);
    edge_pass1<<<NBLK, 256, 0, stream>>>(edge, (const int*)A, pairs, counts,
                                         prefix, ctrl);
    edge_pass2<<<NBLK, 256, 0, stream>>>(pairs, prefix, out32);
    gather_kernel<<<2048, 256, 0, stream>>>(x, st_li, st_gate, out32);
}

// Round 14
// 179.721 us; speedup vs baseline: 2.6703x; 1.2087x over previous
//
#include <hip/hip_runtime.h>
#include <hip/hip_bf16.h>

// Problem constants (match reference)
#define BG    64
#define NPER  4096
#define NTOT  (BG * NPER)       // 262144
#define CC    128
#define EE    4194304
#define KK    3277              // ceil(0.8 * 4096)
#define BK    (BG * KK)         // 209728
#define NBLK  1024              // edge blocks (4096 edges each)

// OUTPUT MODEL (established R0-R9): d_out = out_size 32-BIT words; validation
// reads the UPPER u16 of each word as bf16. Write bf16_bits(v)<<16 per element.
#define OFF_X     0
#define OFF_EDGE  (BK * CC)                 // 26845184  (u32 elements)
#define OFF_BATCH (OFF_EDGE + 2 * EE)       // 35233792
#define OFF_PERM  (OFF_BATCH + BK)          // 35443520

// Scratch carved from the TAIL of chunk 0 (107,380,736 bytes total).
// Consumed by edge kernels, then overwritten by gather (launched after).
#define CH0_BYTES  ((size_t)OFF_EDGE * 4)
#define A_OFF_B    (CH0_BYTES - (size_t)NTOT * 4)        // scores (1 MB)
#define BM_OFF_B   (A_OFF_B - 32768)                      // kept bitmap (32 KB)
#define LP_OFF_B   (BM_OFF_B - 16384)                     // local prefix u16 (16 KB)
#define BO_OFF_B   (LP_OFF_B - 8192)                      // prefix[1025]
#define BC_OFF_B   (LP_OFF_B - 16384)                     // counts[1024]
#define CTRL_OFF_B (LP_OFF_B - 16640)                     // ctrl[2]
#define PAIRS_OFF_B (CTRL_OFF_B - (size_t)NBLK * 4096 * 4) // packed pairs (16.8 MB)

typedef unsigned long long u64;

static __device__ __forceinline__ unsigned short bf16_bits(float f) {
    __hip_bfloat16 h = __float2bfloat16(f);
    return *reinterpret_cast<unsigned short*>(&h);
}
static __device__ __forceinline__ unsigned obf(float v) {
    return ((unsigned)bf16_bits(v)) << 16;   // bf16 in upper half, 0 lower
}
static __device__ __forceinline__ unsigned ald(const unsigned* p) {
    return __hip_atomic_load(p, __ATOMIC_ACQUIRE, __HIP_MEMORY_SCOPE_AGENT);
}
static __device__ __forceinline__ void ast(unsigned* p, unsigned v) {
    __hip_atomic_store(p, v, __ATOMIC_RELEASE, __HIP_MEMORY_SCOPE_AGENT);
}

// Kernel 1: score = x @ coef (f32; 2 rows per wave, float4/lane; f64 accum).
// Also resets the ticket counter each call (graph replay safety).
__global__ void score_kernel(const float* __restrict__ x,
                             const float* __restrict__ coef,
                             float* __restrict__ arr_f,
                             unsigned* __restrict__ ctrl) {
    if (blockIdx.x == 0 && threadIdx.x < 2) ast(&ctrl[threadIdx.x], 0u);

    int lane = threadIdx.x & 63;
    int half = lane >> 5;
    int cg   = lane & 31;
    int waveId = (blockIdx.x * blockDim.x + threadIdx.x) >> 6;
    int nWaves = (gridDim.x * blockDim.x) >> 6;

    float4 c = ((const float4*)coef)[cg];

    for (int pair = waveId; pair < NTOT / 2; pair += nWaves) {
        int row = 2 * pair + half;
        float4 v = ((const float4*)(x + (size_t)row * CC))[cg];
        double s = (double)v.x * c.x + (double)v.y * c.y
                 + (double)v.z * c.z + (double)v.w * c.w;
        #pragma unroll
        for (int off = 16; off > 0; off >>= 1)
            s += __shfl_xor(s, off, 64);     // stays within each 32-lane half
        if (cg == 0) arr_f[row] = (float)s;
    }
}

// ---- Hybrid bitonic sort (4096 keys, 512 threads, 8 keys/thread) ----
template<int J, int K>
__device__ __forceinline__ void bitonic_phase(u64 (&r)[8], u64* lds, int t) {
    if constexpr (J >= 512) {
        __syncthreads();
        #pragma unroll
        for (int m = 0; m < 8; ++m) lds[(t << 3) | m] = r[m];
        __syncthreads();
        #pragma unroll
        for (int m = 0; m < 8; ++m) {
            int i = (t << 3) | m;
            u64 p = lds[i ^ J];
            bool up    = (i & K) == 0;
            bool lower = (i & J) == 0;
            bool takeMax = (lower != up);
            u64 a = r[m];
            r[m] = takeMax ? (a > p ? a : p) : (a < p ? a : p);
        }
    } else if constexpr (J >= 8) {
        constexpr int jl = J >> 3;
        #pragma unroll
        for (int m = 0; m < 8; ++m) {
            u64 p = __shfl_xor(r[m], jl, 64);
            int i = (t << 3) | m;
            bool up    = (i & K) == 0;
            bool lower = (i & J) == 0;
            bool takeMax = (lower != up);
            u64 a = r[m];
            r[m] = takeMax ? (a > p ? a : p) : (a < p ? a : p);
        }
    } else {
        #pragma unroll
        for (int m = 0; m < 8; ++m) {
            if ((m & J) == 0) {
                int i = (t << 3) | m;
                bool up = (i & K) == 0;
                u64 a = r[m], c = r[m | J];
                if ((a > c) == up) { r[m] = c; r[m | J] = a; }
            }
        }
    }
    if constexpr (J > 1) bitonic_phase<J / 2, K>(r, lds, t);
}

template<int K>
__device__ __forceinline__ void bitonic_stage(u64 (&r)[8], u64* lds, int t) {
    bitonic_phase<K / 2, K>(r, lds, t);
    if constexpr (K < 4096) bitonic_stage<K * 2>(r, lds, t);
}

// Kernel 2: per-graph top-K (descending score, tie -> lower index).
// Emits: staged (li, gate) by rank, kept-BITMAP (128 words/graph) and local
// prefix counts (u16/word) for the edge kernel's LDS rank structure.
__global__ __launch_bounds__(512) void topk_kernel(const float* __restrict__ arr_f,
                                                   unsigned* __restrict__ st_li,
                                                   unsigned* __restrict__ st_gate,
                                                   unsigned* __restrict__ bm_g,
                                                   unsigned short* __restrict__ lp_g) {
    __shared__ u64 lds[NPER];
    __shared__ unsigned lbm[128];
    __shared__ unsigned lpc[128];
    int b = blockIdx.x;
    int t = threadIdx.x;
    const float* s = arr_f + (b << 12);

    float4 v0 = *(const float4*)(s + (t << 3));
    float4 v1 = *(const float4*)(s + (t << 3) + 4);
    float vv[8] = {v0.x, v0.y, v0.z, v0.w, v1.x, v1.y, v1.z, v1.w};
    u64 r[8];
    #pragma unroll
    for (int m = 0; m < 8; ++m) {
        unsigned u = __float_as_uint(vv[m]);
        u = u ^ ((u >> 31) ? 0xFFFFFFFFu : 0x80000000u);  // order-preserving asc
        u = ~u;                                            // descending
        r[m] = ((u64)u << 32) | (unsigned)((t << 3) | m);
    }

    bitonic_stage<2>(r, lds, t);

    if (t < 128) lbm[t] = 0u;
    __syncthreads();

    #pragma unroll
    for (int m = 0; m < 8; ++m) {
        int rank = (t << 3) | m;
        if (rank < KK) {
            int li = (int)(r[m] & 0xFFFFFFFFull);
            int j = b * KK + rank;
            unsigned tt = ~((unsigned)(r[m] >> 32));       // recover exact f32 score
            unsigned u0 = (tt >> 31) ? (tt ^ 0x80000000u) : ~tt;
            float sc = __uint_as_float(u0);
            float gate = 1.0f / (1.0f + expf(-sc));
            st_li[j]   = (unsigned)li;
            st_gate[j] = __float_as_uint(gate);
            atomicOr(&lbm[li >> 5], 1u << (li & 31));
        }
    }
    __syncthreads();

    if (t < 128) lpc[t] = __popc(lbm[t]);
    __syncthreads();
    #pragma unroll
    for (int off = 1; off < 128; off <<= 1) {
        unsigned add = (t < 128 && t >= off) ? lpc[t - off] : 0u;
        __syncthreads();
        if (t < 128) lpc[t] += add;
        __syncthreads();
    }
    if (t < 128) {
        unsigned w = lbm[t];
        bm_g[(b << 7) + t] = w;
        lp_g[(b << 7) + t] = (unsigned short)(lpc[t] - __popc(w));  // exclusive
    }
}

// Kernel 3: edge pass 1 — LDS-resident rank structure (48 KB), single streaming
// edge read, local stable compaction of packed bf16 pairs, publish count.
// Last-arriving block (ticket) scans counts into prefix[]; NOBODY waits
// (R12 lesson: grid-wide spins are a 10x regression).
__global__ __launch_bounds__(256) void edge_pass1(
        const int* __restrict__ edge,
        const unsigned* __restrict__ bm_g,
        const unsigned short* __restrict__ lp_g,
        unsigned* __restrict__ pairs,
        unsigned* __restrict__ counts,
        unsigned* __restrict__ prefix,
        unsigned* __restrict__ ctrl) {
    __shared__ unsigned sBm[8192];          // 32 KB kept-bitmap
    __shared__ unsigned short sLp[8192];    // 16 KB local prefixes
    __shared__ u64 sBal[4][16];
    __shared__ unsigned sScan[256];
    __shared__ int sTicket;

    int b = blockIdx.x;
    int base = b << 12;
    int tid = threadIdx.x;
    int lane = tid & 63, wid = tid >> 6;
    u64 lmask = (1ull << lane) - 1ull;

    for (int i = tid; i < 8192; i += 256) sBm[i] = bm_g[i];
    for (int i = tid; i < 4096; i += 256)
        ((unsigned*)sLp)[i] = ((const unsigned*)lp_g)[i];
    __syncthreads();

    unsigned wpk[16];
    unsigned vmask = 0;
    #pragma unroll
    for (int k = 0; k < 16; ++k) {
        int e0 = edge[base + (k << 8) + tid];
        int e1 = edge[EE + base + (k << 8) + tid];
        unsigned w0 = sBm[e0 >> 5], w1 = sBm[e1 >> 5];
        bool valid = ((w0 >> (e0 & 31)) & (w1 >> (e1 & 31)) & 1u) != 0u;
        u64 bal = __ballot(valid);
        if (lane == 0) sBal[wid][k] = bal;
        unsigned j0 = (unsigned)(e0 >> 12) * KK + sLp[e0 >> 5]
                    + (unsigned)__popc(w0 & ((1u << (e0 & 31)) - 1u));
        unsigned j1 = (unsigned)(e1 >> 12) * KK + sLp[e1 >> 5]
                    + (unsigned)__popc(w1 & ((1u << (e1 & 31)) - 1u));
        wpk[k] = obf((float)j0) | (unsigned)bf16_bits((float)j1);
        vmask |= (valid ? 1u : 0u) << k;
    }
    __syncthreads();

    unsigned kwBase[16];
    unsigned cnt = 0;
    #pragma unroll
    for (int k = 0; k < 16; ++k) {
        unsigned p0 = (unsigned)__popcll(sBal[0][k]);
        unsigned p1 = (unsigned)__popcll(sBal[1][k]);
        unsigned p2 = (unsigned)__popcll(sBal[2][k]);
        unsigned p3 = (unsigned)__popcll(sBal[3][k]);
        unsigned wb = (wid > 0 ? p0 : 0u) + (wid > 1 ? p1 : 0u) + (wid > 2 ? p2 : 0u);
        kwBase[k] = cnt + wb;
        cnt += p0 + p1 + p2 + p3;
    }

    unsigned* pb = pairs + base;
    #pragma unroll
    for (int k = 0; k < 16; ++k) {
        if ((vmask >> k) & 1u) {
            unsigned vp = kwBase[k] + (unsigned)__popcll(sBal[wid][k] & lmask);
            pb[vp] = wpk[k];
        }
    }

    if (tid == 0) {
        ast(&counts[b], cnt);
        sTicket = (int)__hip_atomic_fetch_add(&ctrl[0], 1u, __ATOMIC_ACQ_REL,
                                              __HIP_MEMORY_SCOPE_AGENT);
    }
    __syncthreads();

    if (sTicket == NBLK - 1) {     // last block: scan counts -> prefix (no waiting)
        unsigned v0 = ald(&counts[tid * 4 + 0]);
        unsigned v1 = ald(&counts[tid * 4 + 1]);
        unsigned v2 = ald(&counts[tid * 4 + 2]);
        unsigned v3 = ald(&counts[tid * 4 + 3]);
        unsigned s0 = v0, s1 = s0 + v1, s2 = s1 + v2, s3 = s2 + v3;
        sScan[tid] = s3;
        __syncthreads();
        #pragma unroll
        for (int off = 1; off < 256; off <<= 1) {
            unsigned add = (tid >= off) ? sScan[tid - off] : 0u;
            __syncthreads();
            sScan[tid] += add;
            __syncthreads();
        }
        unsigned before = tid ? sScan[tid - 1] : 0u;
        prefix[tid * 4 + 0] = before;
        prefix[tid * 4 + 1] = before + s0;
        prefix[tid * 4 + 2] = before + s1;
        prefix[tid * 4 + 3] = before + s2;
        if (tid == 255) prefix[NBLK] = before + s3;
    }
}

// Kernel 4: edge pass 2 — pure streaming. Front: copy packed pairs to
// [prefix[b], prefix[b]+cnt). Tail: contiguous -1 fill.
__global__ __launch_bounds__(256) void edge_pass2(
        const unsigned* __restrict__ pairs,
        const unsigned* __restrict__ prefix,
        unsigned* __restrict__ out32) {
    int b = blockIdx.x;
    unsigned base = (unsigned)(b << 12);
    unsigned tid = threadIdx.x;
    unsigned blockOff = prefix[b];
    unsigned cnt = prefix[b + 1] - blockOff;
    unsigned nvalid = prefix[NBLK];
    unsigned* oe = out32 + OFF_EDGE;
    const unsigned* pb = pairs + base;

    for (unsigned i = tid; i < cnt; i += 256u) {
        unsigned w = pb[i];
        oe[blockOff + i]      = w & 0xFFFF0000u;
        oe[EE + blockOff + i] = w << 16;
    }
    unsigned tailBase = nvalid + base - blockOff;
    unsigned tcnt = 4096u - cnt;
    unsigned NEG1 = obf(-1.0f);
    for (unsigned i = tid; i < tcnt; i += 256u) {
        oe[tailBase + i]      = NEG1;
        oe[EE + tailBase + i] = NEG1;
    }
}

// Kernel 5: gather + finalize. x_pooled = bf16(x[perm]*gate); cg==0 lane also
// rewrites batch/perm in place AFTER its group's reads (same-wave program
// order -> race-free).
__global__ void gather_kernel(const float* __restrict__ x,
                              const unsigned* __restrict__ st_li,
                              const unsigned* __restrict__ st_gate,
                              unsigned* __restrict__ out32) {
    int tid = blockIdx.x * blockDim.x + threadIdx.x;
    int rowsPerGrid = (gridDim.x * blockDim.x) >> 5;
    int rid = tid >> 5;
    int cg  = tid & 31;

    for (int row = rid; row < BK; row += rowsPerGrid) {
        int b  = row / KK;
        int li = (int)st_li[row];
        int node = (b << 12) + li;
        float g = __uint_as_float(st_gate[row]);
        float4 v = ((const float4*)(x + (size_t)node * CC))[cg];
        uint4 o;
        o.x = obf(v.x * g);
        o.y = obf(v.y * g);
        o.z = obf(v.z * g);
        o.w = obf(v.w * g);
        ((uint4*)(out32 + OFF_X))[(size_t)row * 32 + cg] = o;
        if (cg == 0) {
            out32[OFF_BATCH + row] = obf((float)b);
            out32[OFF_PERM + row]  = obf((float)node);
        }
    }
}

extern "C" void kernel_launch(void* const* d_in, const int* in_sizes, int n_in,
                              void* d_out, int out_size, void* d_ws, size_t ws_size,
                              hipStream_t stream) {
    // Resolve inputs by element count (all distinct; proven working R5+).
    const float* x    = nullptr;   // 33,554,432 f32
    const float* coef = nullptr;   // 128 f32
    const int*   edge = nullptr;   // 8,388,608 int32
    for (int i = 0; i < n_in; ++i) {
        switch (in_sizes[i]) {
            case NTOT * CC: x    = (const float*)d_in[i]; break;
            case CC:        coef = (const float*)d_in[i]; break;
            case 2 * EE:    edge = (const int*)d_in[i];   break;
            default: break; // batch unused (static layout 64 x 4096)
        }
    }
    if (!x || !coef || !edge) return;

    char* ob = (char*)d_out;
    unsigned* out32 = (unsigned*)d_out;
    float*          A      = (float*)(ob + A_OFF_B);
    unsigned*       bm_g   = (unsigned*)(ob + BM_OFF_B);
    unsigned short* lp_g   = (unsigned short*)(ob + LP_OFF_B);
    unsigned*       counts = (unsigned*)(ob + BC_OFF_B);
    unsigned*       prefix = (unsigned*)(ob + BO_OFF_B);
    unsigned*       ctrl   = (unsigned*)(ob + CTRL_OFF_B);
    unsigned*       pairs  = (unsigned*)(ob + PAIRS_OFF_B);
    unsigned* st_li   = out32 + OFF_BATCH;   // staged li   (raw u32)
    unsigned* st_gate = out32 + OFF_PERM;    // staged gate (f32 bits)

    score_kernel<<<2048, 256, 0, stream>>>(x, coef, A, ctrl);
    topk_kernel<<<BG, 512, 0, stream>>>(A, st_li, st_gate, bm_g, lp_g);
    edge_pass1<<<NBLK, 256, 0, stream>>>(edge, bm_g, lp_g, pairs, counts,
                                         prefix, ctrl);
    edge_pass2<<<NBLK, 256, 0, stream>>>(pairs, prefix, out32);
    gather_kernel<<<2048, 256, 0, stream>>>(x, st_li, st_gate, out32);
}

// Round 15
// 147.793 us; speedup vs baseline: 3.2472x; 1.2160x over previous
//
#include <hip/hip_runtime.h>
#include <hip/hip_bf16.h>

// Problem constants (match reference)
#define BG    64
#define NPER  4096
#define NTOT  (BG * NPER)       // 262144
#define CC    128
#define EE    4194304
#define KK    3277              // ceil(0.8 * 4096)
#define BK    (BG * KK)         // 209728
#define NBLK  512               // edge blocks (8192 edges each)
#define EPB   8192

// OUTPUT MODEL (established R0-R9): d_out = out_size 32-BIT words; validation
// reads the UPPER u16 of each word as bf16. Write bf16_bits(v)<<16 per element.
#define OFF_X     0
#define OFF_EDGE  (BK * CC)                 // 26845184  (u32 elements)
#define OFF_BATCH (OFF_EDGE + 2 * EE)       // 35233792
#define OFF_PERM  (OFF_BATCH + BK)          // 35443520

// Scratch carved from the TAIL of chunk 0 (107,380,736 bytes total).
// Consumed by edge kernels, then overwritten by gather (launched after).
#define CH0_BYTES  ((size_t)OFF_EDGE * 4)
#define A_OFF_B    (CH0_BYTES - (size_t)NTOT * 4)        // scores (1 MB)
#define BM_OFF_B   (A_OFF_B - 32768)                      // kept bitmap (32 KB)
#define LP_OFF_B   (BM_OFF_B - 16384)                     // local prefix u16 (16 KB)
#define BO_OFF_B   (LP_OFF_B - 8192)                      // prefix[513]
#define BC_OFF_B   (LP_OFF_B - 16384)                     // counts[512]
#define CTRL_OFF_B (LP_OFF_B - 16640)                     // ctrl[2]
#define PAIRS_OFF_B (CTRL_OFF_B - (size_t)EE * 4)         // packed pairs (16.8 MB)

typedef unsigned long long u64;

static __device__ __forceinline__ unsigned short bf16_bits(float f) {
    __hip_bfloat16 h = __float2bfloat16(f);
    return *reinterpret_cast<unsigned short*>(&h);
}
static __device__ __forceinline__ unsigned obf(float v) {
    return ((unsigned)bf16_bits(v)) << 16;   // bf16 in upper half, 0 lower
}
static __device__ __forceinline__ unsigned ald(const unsigned* p) {
    return __hip_atomic_load(p, __ATOMIC_ACQUIRE, __HIP_MEMORY_SCOPE_AGENT);
}
static __device__ __forceinline__ void ast(unsigned* p, unsigned v) {
    __hip_atomic_store(p, v, __ATOMIC_RELEASE, __HIP_MEMORY_SCOPE_AGENT);
}

// Kernel 1: score = x @ coef (f32; 2 rows per wave, float4/lane; f64 accum).
// Also resets the ticket counter each call (graph replay safety).
__global__ void score_kernel(const float* __restrict__ x,
                             const float* __restrict__ coef,
                             float* __restrict__ arr_f,
                             unsigned* __restrict__ ctrl) {
    if (blockIdx.x == 0 && threadIdx.x < 2) ast(&ctrl[threadIdx.x], 0u);

    int lane = threadIdx.x & 63;
    int half = lane >> 5;
    int cg   = lane & 31;
    int waveId = (blockIdx.x * blockDim.x + threadIdx.x) >> 6;
    int nWaves = (gridDim.x * blockDim.x) >> 6;

    float4 c = ((const float4*)coef)[cg];

    for (int pair = waveId; pair < NTOT / 2; pair += nWaves) {
        int row = 2 * pair + half;
        float4 v = ((const float4*)(x + (size_t)row * CC))[cg];
        double s = (double)v.x * c.x + (double)v.y * c.y
                 + (double)v.z * c.z + (double)v.w * c.w;
        #pragma unroll
        for (int off = 16; off > 0; off >>= 1)
            s += __shfl_xor(s, off, 64);     // stays within each 32-lane half
        if (cg == 0) arr_f[row] = (float)s;
    }
}

// ---- Hybrid bitonic sort (4096 keys, 512 threads, 8 keys/thread) ----
template<int J, int K>
__device__ __forceinline__ void bitonic_phase(u64 (&r)[8], u64* lds, int t) {
    if constexpr (J >= 512) {
        __syncthreads();
        #pragma unroll
        for (int m = 0; m < 8; ++m) lds[(t << 3) | m] = r[m];
        __syncthreads();
        #pragma unroll
        for (int m = 0; m < 8; ++m) {
            int i = (t << 3) | m;
            u64 p = lds[i ^ J];
            bool up    = (i & K) == 0;
            bool lower = (i & J) == 0;
            bool takeMax = (lower != up);
            u64 a = r[m];
            r[m] = takeMax ? (a > p ? a : p) : (a < p ? a : p);
        }
    } else if constexpr (J >= 8) {
        constexpr int jl = J >> 3;
        #pragma unroll
        for (int m = 0; m < 8; ++m) {
            u64 p = __shfl_xor(r[m], jl, 64);
            int i = (t << 3) | m;
            bool up    = (i & K) == 0;
            bool lower = (i & J) == 0;
            bool takeMax = (lower != up);
            u64 a = r[m];
            r[m] = takeMax ? (a > p ? a : p) : (a < p ? a : p);
        }
    } else {
        #pragma unroll
        for (int m = 0; m < 8; ++m) {
            if ((m & J) == 0) {
                int i = (t << 3) | m;
                bool up = (i & K) == 0;
                u64 a = r[m], c = r[m | J];
                if ((a > c) == up) { r[m] = c; r[m | J] = a; }
            }
        }
    }
    if constexpr (J > 1) bitonic_phase<J / 2, K>(r, lds, t);
}

template<int K>
__device__ __forceinline__ void bitonic_stage(u64 (&r)[8], u64* lds, int t) {
    bitonic_phase<K / 2, K>(r, lds, t);
    if constexpr (K < 4096) bitonic_stage<K * 2>(r, lds, t);
}

// Kernel 2: per-graph top-K (descending score, tie -> lower index).
// Emits: staged (li, gate) by rank, kept-BITMAP + local prefix for the edge
// kernel's LDS rank structure.
__global__ __launch_bounds__(512) void topk_kernel(const float* __restrict__ arr_f,
                                                   unsigned* __restrict__ st_li,
                                                   unsigned* __restrict__ st_gate,
                                                   unsigned* __restrict__ bm_g,
                                                   unsigned short* __restrict__ lp_g) {
    __shared__ u64 lds[NPER];
    __shared__ unsigned lbm[128];
    __shared__ unsigned lpc[128];
    int b = blockIdx.x;
    int t = threadIdx.x;
    const float* s = arr_f + (b << 12);

    float4 v0 = *(const float4*)(s + (t << 3));
    float4 v1 = *(const float4*)(s + (t << 3) + 4);
    float vv[8] = {v0.x, v0.y, v0.z, v0.w, v1.x, v1.y, v1.z, v1.w};
    u64 r[8];
    #pragma unroll
    for (int m = 0; m < 8; ++m) {
        unsigned u = __float_as_uint(vv[m]);
        u = u ^ ((u >> 31) ? 0xFFFFFFFFu : 0x80000000u);  // order-preserving asc
        u = ~u;                                            // descending
        r[m] = ((u64)u << 32) | (unsigned)((t << 3) | m);
    }

    bitonic_stage<2>(r, lds, t);

    if (t < 128) lbm[t] = 0u;
    __syncthreads();

    #pragma unroll
    for (int m = 0; m < 8; ++m) {
        int rank = (t << 3) | m;
        if (rank < KK) {
            int li = (int)(r[m] & 0xFFFFFFFFull);
            int j = b * KK + rank;
            unsigned tt = ~((unsigned)(r[m] >> 32));       // recover exact f32 score
            unsigned u0 = (tt >> 31) ? (tt ^ 0x80000000u) : ~tt;
            float sc = __uint_as_float(u0);
            float gate = 1.0f / (1.0f + expf(-sc));
            st_li[j]   = (unsigned)li;
            st_gate[j] = __float_as_uint(gate);
            atomicOr(&lbm[li >> 5], 1u << (li & 31));
        }
    }
    __syncthreads();

    if (t < 128) lpc[t] = __popc(lbm[t]);
    __syncthreads();
    #pragma unroll
    for (int off = 1; off < 128; off <<= 1) {
        unsigned add = (t < 128 && t >= off) ? lpc[t - off] : 0u;
        __syncthreads();
        if (t < 128) lpc[t] += add;
        __syncthreads();
    }
    if (t < 128) {
        unsigned w = lbm[t];
        bm_g[(b << 7) + t] = w;
        lp_g[(b << 7) + t] = (unsigned short)(lpc[t] - __popc(w));  // exclusive
    }
}

// Kernel 3: edge pass 1 — 512 blocks x 512 threads (2/CU, ONE round, no tail;
// R14 lesson: 1.33 rounds halves effective throughput). LDS rank structure,
// explicit 16-deep load prefetch per half, conditional relabel lookups.
// Last-arriving block (ticket) scans counts into prefix[]; nobody waits.
__global__ __launch_bounds__(512, 4) void edge_pass1(
        const int* __restrict__ edge,
        const unsigned* __restrict__ bm_g,
        const unsigned short* __restrict__ lp_g,
        unsigned* __restrict__ pairs,
        unsigned* __restrict__ counts,
        unsigned* __restrict__ prefix,
        unsigned* __restrict__ ctrl) {
    __shared__ unsigned sBm[8192];          // 32 KB kept-bitmap
    __shared__ unsigned short sLp[8192];    // 16 KB local prefixes
    __shared__ u64 sBal[8][16];
    __shared__ unsigned sScan[512];
    __shared__ int sTicket;

    int b = blockIdx.x;
    int base = b << 13;
    int tid = threadIdx.x;
    int lane = tid & 63, wid = tid >> 6;
    u64 lmask = (1ull << lane) - 1ull;

    for (int i = tid; i < 8192; i += 512) sBm[i] = bm_g[i];
    for (int i = tid; i < 4096; i += 512)
        ((unsigned*)sLp)[i] = ((const unsigned*)lp_g)[i];
    __syncthreads();

    unsigned wpk[16];
    unsigned vmask = 0;
    #pragma unroll
    for (int h = 0; h < 2; ++h) {
        int ev0[8], ev1[8];
        #pragma unroll
        for (int kk = 0; kk < 8; ++kk) {       // 16 loads in flight
            int k = (h << 3) + kk;
            ev0[kk] = edge[base + (k << 9) + tid];
            ev1[kk] = edge[EE + base + (k << 9) + tid];
        }
        #pragma unroll
        for (int kk = 0; kk < 8; ++kk) {
            int k = (h << 3) + kk;
            int e0 = ev0[kk], e1 = ev1[kk];
            unsigned w0 = sBm[e0 >> 5], w1 = sBm[e1 >> 5];
            bool valid = ((w0 >> (e0 & 31)) & (w1 >> (e1 & 31)) & 1u) != 0u;
            u64 bal = __ballot(valid);
            if (lane == 0) sBal[wid][k] = bal;
            unsigned pk = 0;
            if (valid) {                        // relabel only kept edges
                unsigned j0 = (unsigned)(e0 >> 12) * KK + sLp[e0 >> 5]
                            + (unsigned)__popc(w0 & ((1u << (e0 & 31)) - 1u));
                unsigned j1 = (unsigned)(e1 >> 12) * KK + sLp[e1 >> 5]
                            + (unsigned)__popc(w1 & ((1u << (e1 & 31)) - 1u));
                pk = obf((float)j0) | (unsigned)bf16_bits((float)j1);
            }
            wpk[k] = pk;
            vmask |= (valid ? 1u : 0u) << k;
        }
    }
    __syncthreads();

    // fused block-prefix + stable scatter of packed pairs
    unsigned* pb = pairs + base;
    unsigned run = 0;
    #pragma unroll
    for (int k = 0; k < 16; ++k) {
        unsigned tot = 0, wb = 0;
        #pragma unroll
        for (int w = 0; w < 8; ++w) {
            unsigned p = (unsigned)__popcll(sBal[w][k]);
            if (w < wid) wb += p;
            tot += p;
        }
        if ((vmask >> k) & 1u) {
            unsigned vp = run + wb + (unsigned)__popcll(sBal[wid][k] & lmask);
            pb[vp] = wpk[k];
        }
        run += tot;
    }

    if (tid == 0) {
        ast(&counts[b], run);
        sTicket = (int)__hip_atomic_fetch_add(&ctrl[0], 1u, __ATOMIC_ACQ_REL,
                                              __HIP_MEMORY_SCOPE_AGENT);
    }
    __syncthreads();

    if (sTicket == NBLK - 1) {     // last block: scan counts -> prefix (no waiting)
        unsigned v = ald(&counts[tid]);
        sScan[tid] = v;
        __syncthreads();
        #pragma unroll
        for (int off = 1; off < 512; off <<= 1) {
            unsigned add = (tid >= off) ? sScan[tid - off] : 0u;
            __syncthreads();
            sScan[tid] += add;
            __syncthreads();
        }
        prefix[tid] = sScan[tid] - v;              // exclusive
        if (tid == 511) prefix[NBLK] = sScan[511]; // total valid
    }
}

// Kernel 4: edge pass 2 — pure streaming. Front: copy packed pairs to
// [prefix[b], prefix[b]+cnt). Tail: contiguous -1 fill.
__global__ __launch_bounds__(256) void edge_pass2(
        const unsigned* __restrict__ pairs,
        const unsigned* __restrict__ prefix,
        unsigned* __restrict__ out32) {
    int b = blockIdx.x;
    unsigned base = (unsigned)(b << 13);
    unsigned tid = threadIdx.x;
    unsigned blockOff = prefix[b];
    unsigned cnt = prefix[b + 1] - blockOff;
    unsigned nvalid = prefix[NBLK];
    unsigned* oe = out32 + OFF_EDGE;
    const unsigned* pb = pairs + base;

    for (unsigned i = tid; i < cnt; i += 256u) {
        unsigned w = pb[i];
        oe[blockOff + i]      = w & 0xFFFF0000u;
        oe[EE + blockOff + i] = w << 16;
    }
    unsigned tailBase = nvalid + base - blockOff;
    unsigned tcnt = (unsigned)EPB - cnt;
    unsigned NEG1 = obf(-1.0f);
    for (unsigned i = tid; i < tcnt; i += 256u) {
        oe[tailBase + i]      = NEG1;
        oe[EE + tailBase + i] = NEG1;
    }
}

// Kernel 5: gather + finalize. x_pooled = bf16(x[perm]*gate); cg==0 lane also
// rewrites batch/perm in place AFTER its group's reads (same-wave program
// order -> race-free).
__global__ void gather_kernel(const float* __restrict__ x,
                              const unsigned* __restrict__ st_li,
                              const unsigned* __restrict__ st_gate,
                              unsigned* __restrict__ out32) {
    int tid = blockIdx.x * blockDim.x + threadIdx.x;
    int rowsPerGrid = (gridDim.x * blockDim.x) >> 5;
    int rid = tid >> 5;
    int cg  = tid & 31;

    for (int row = rid; row < BK; row += rowsPerGrid) {
        int b  = row / KK;
        int li = (int)st_li[row];
        int node = (b << 12) + li;
        float g = __uint_as_float(st_gate[row]);
        float4 v = ((const float4*)(x + (size_t)node * CC))[cg];
        uint4 o;
        o.x = obf(v.x * g);
        o.y = obf(v.y * g);
        o.z = obf(v.z * g);
        o.w = obf(v.w * g);
        ((uint4*)(out32 + OFF_X))[(size_t)row * 32 + cg] = o;
        if (cg == 0) {
            out32[OFF_BATCH + row] = obf((float)b);
            out32[OFF_PERM + row]  = obf((float)node);
        }
    }
}

extern "C" void kernel_launch(void* const* d_in, const int* in_sizes, int n_in,
                              void* d_out, int out_size, void* d_ws, size_t ws_size,
                              hipStream_t stream) {
    // Resolve inputs by element count (all distinct; proven working R5+).
    const float* x    = nullptr;   // 33,554,432 f32
    const float* coef = nullptr;   // 128 f32
    const int*   edge = nullptr;   // 8,388,608 int32
    for (int i = 0; i < n_in; ++i) {
        switch (in_sizes[i]) {
            case NTOT * CC: x    = (const float*)d_in[i]; break;
            case CC:        coef = (const float*)d_in[i]; break;
            case 2 * EE:    edge = (const int*)d_in[i];   break;
            default: break; // batch unused (static layout 64 x 4096)
        }
    }
    if (!x || !coef || !edge) return;

    char* ob = (char*)d_out;
    unsigned* out32 = (unsigned*)d_out;
    float*          A      = (float*)(ob + A_OFF_B);
    unsigned*       bm_g   = (unsigned*)(ob + BM_OFF_B);
    unsigned short* lp_g   = (unsigned short*)(ob + LP_OFF_B);
    unsigned*       counts = (unsigned*)(ob + BC_OFF_B);
    unsigned*       prefix = (unsigned*)(ob + BO_OFF_B);
    unsigned*       ctrl   = (unsigned*)(ob + CTRL_OFF_B);
    unsigned*       pairs  = (unsigned*)(ob + PAIRS_OFF_B);
    unsigned* st_li   = out32 + OFF_BATCH;   // staged li   (raw u32)
    unsigned* st_gate = out32 + OFF_PERM;    // staged gate (f32 bits)

    score_kernel<<<2048, 256, 0, stream>>>(x, coef, A, ctrl);
    topk_kernel<<<BG, 512, 0, stream>>>(A, st_li, st_gate, bm_g, lp_g);
    edge_pass1<<<NBLK, 512, 0, stream>>>(edge, bm_g, lp_g, pairs, counts,
                                         prefix, ctrl);
    edge_pass2<<<NBLK, 256, 0, stream>>>(pairs, prefix, out32);
    gather_kernel<<<2048, 256, 0, stream>>>(x, st_li, st_gate, out32);
}